// Round 10
// baseline (75.199 us; speedup 1.0000x reference)
//
#include <hip/hip_runtime.h>

// ---------------------------------------------------------------------------
// DeepFFM round 10: 5 launches.
//  1) prep_a   : X->bf16(pad), W0/W1/W2 -> bf16^T, nfkT transpose (bf16)
//  2) prep_b   : Mt build from nfkT; block b does rows {b, 1023-b} (balanced)
//  3) gemm12   : [T-partials | h0] = Xb @ [Mt ; Wt0]^T, N=2048, tri-K-skip
//                NEW: BM=256 x BN=128, 8 waves (512 thr), 96KB dbuf ->
//                grid 256 = 1 block/CU; staging traffic -25%
//  4) gemm3    : h1 = relu(h0 @ W1 + B1)   (64x64, 512 blocks)
//  5) gemm4    : BN=256 (full N) + fused out-dot + finalize -> out[]
// GEMMs: bf16 MFMA 16x16x32, fp32 acc, double-buffered LDS, R6-proven
// prefetch loop (stage(t+1) before compute(t), ONE barrier per K-tile),
// XOR-swizzled LDS, XCD-chunked blockIdx swizzle (all grids %8==0).
// ---------------------------------------------------------------------------

#define BATCH   4096
#define FSZ     1000
#define NFIELDS 39
#define KDIM    40

typedef __attribute__((ext_vector_type(8))) short short8v;  // 8 x bf16
typedef __attribute__((ext_vector_type(4))) float f32x4;

__device__ __forceinline__ short f2bf(float f) {
  unsigned u = __builtin_bit_cast(unsigned, f);
  u += 0x7fff + ((u >> 16) & 1);   // RNE (finite data)
  return (short)(u >> 16);
}
__device__ __forceinline__ float bf2f(unsigned short h) {
  unsigned u = (unsigned)h << 16;
  return __builtin_bit_cast(float, u);
}

typedef const __attribute__((address_space(1))) unsigned int* gas_ptr;
typedef __attribute__((address_space(3))) unsigned int* las_ptr;
__device__ __forceinline__ void gload16(const void* g, void* l) {
  __builtin_amdgcn_global_load_lds((gas_ptr)g, (las_ptr)l, 16, 0, 0);
}

// ---------------------------------------------------------------------------
// prep_a: block ranges
//  [0,4096)     : Xb row conversion (1000 -> 1024 pad)
//  [4096,5120)  : W0^T -> B12 rows 1024..2047
//  [5120,5632)  : W1^T -> Wt1
//  [5632,5760)  : W2^T -> Wt2
//  [5760,5916)  : nfkT[g][j][k] = bf16(nfk[j][g][k])  (39g x 4 j-chunks)
// ---------------------------------------------------------------------------
__device__ __forceinline__ void transp32(
    const float* __restrict__ in, short* __restrict__ out, int idx, int nx,
    int K_in, int N_in, int Kpad, float (*t)[33], int tid)
{
  int n0 = (idx % nx) * 32, k0 = (idx / nx) * 32;
  int tx = tid & 31, ty = tid >> 5;
  #pragma unroll
  for (int i = 0; i < 32; i += 8) {
    int k = k0 + ty + i, n = n0 + tx;
    t[ty + i][tx] = (k < K_in && n < N_in) ? in[(size_t)k * N_in + n] : 0.f;
  }
  __syncthreads();
  #pragma unroll
  for (int i = 0; i < 32; i += 8) {
    int n = n0 + ty + i, k = k0 + tx;
    if (n < N_in && k < Kpad) out[(size_t)n * Kpad + k] = f2bf(t[tx][ty + i]);
  }
}

__global__ __launch_bounds__(256) void prep_a_kernel(
    const float* __restrict__ X, const float* __restrict__ nfk,
    const float* __restrict__ W0, const float* __restrict__ W1,
    const float* __restrict__ W2,
    short* __restrict__ Xb, short* __restrict__ B12,
    short* __restrict__ Wt1, short* __restrict__ Wt2,
    unsigned short* __restrict__ nfkT)
{
  __shared__ float tbuf[32][33];
  const int bid = blockIdx.x, tid = threadIdx.x;
  if (bid < 4096) {
    int k = tid * 4;
    short4 o = make_short4(0, 0, 0, 0);
    if (k < FSZ) {
      float4 v = *(const float4*)(X + (size_t)bid * FSZ + k);
      o = make_short4(f2bf(v.x), f2bf(v.y), f2bf(v.z), f2bf(v.w));
    }
    *(short4*)(Xb + (size_t)bid * 1024 + k) = o;
  } else if (bid < 5120) {
    transp32(W0, B12 + 1024 * 1024, bid - 4096, 32, 1000, 1024, 1024, tbuf, tid);
  } else if (bid < 5632) {
    transp32(W1, Wt1, bid - 5120, 16, 1024, 512, 1024, tbuf, tid);
  } else if (bid < 5760) {
    transp32(W2, Wt2, bid - 5632, 8, 512, 256, 512, tbuf, tid);
  } else {
    // nfkT transpose (f32 -> bf16): read nfk[j][g][:], write coalesced rows
    int idx = bid - 5760;
    int g = idx >> 2, jc = idx & 3;
    int j = jc * 256 + tid;
    if (j < FSZ && g < NFIELDS) {
      const float4* src = (const float4*)(nfk + ((size_t)j * NFIELDS + g) * KDIM);
      short4* dst = (short4*)(nfkT + ((size_t)g * FSZ + j) * KDIM);
      #pragma unroll
      for (int t = 0; t < KDIM / 4; ++t) {
        float4 v = src[t];
        dst[t] = make_short4(f2bf(v.x), f2bf(v.y), f2bf(v.z), f2bf(v.w));
      }
    }
  }
}

// ---------------------------------------------------------------------------
// prep_b: Mt rows {b, 1023-b} per block (balanced ~1023 cols total).
// nfk[n] cached f32 in LDS (q side); p side reads bf16 nfkT rows coalesced.
// ---------------------------------------------------------------------------
__global__ __launch_bounds__(256) void prep_b_kernel(
    const float* __restrict__ nfk, const unsigned short* __restrict__ nfkT,
    const int* __restrict__ f2f, short* __restrict__ B12)
{
  __shared__ float C[NFIELDS * 44];  // nfk[n,:,:], stride 44 (16B-aligned)
  const int tid = threadIdx.x;
  #pragma unroll
  for (int ri = 0; ri < 2; ++ri) {
    const int n = ri ? (1023 - (int)blockIdx.x) : (int)blockIdx.x;
    __syncthreads();                       // prior C readers done
    if (n < FSZ) {
      for (int t = tid; t < NFIELDS * KDIM; t += 256)
        C[(t / KDIM) * 44 + (t % KDIM)] = nfk[(size_t)n * (NFIELDS * KDIM) + t];
    }
    __syncthreads();
    int fn = (n < FSZ) ? f2f[n] : 0;
    const unsigned short* pbase = nfkT + (size_t)fn * FSZ * KDIM;
    #pragma unroll
    for (int kk = 0; kk < 4; ++kk) {
      int k = kk * 256 + tid;
      float s = 0.f;
      if (n < FSZ && k < n) {
        int fk = f2f[k];
        const short8v* p = (const short8v*)(pbase + (size_t)k * KDIM);
        const float* q = &C[fk * 44];
        #pragma unroll
        for (int t = 0; t < 5; ++t) {
          short8v v = p[t];
          #pragma unroll
          for (int e = 0; e < 8; ++e)
            s = fmaf(bf2f((unsigned short)v[e]), q[t * 8 + e], s);
        }
      }
      B12[(size_t)n * 1024 + k] = f2bf(s);
    }
  }
}

// ---------------------------------------------------------------------------
// bf16 MFMA GEMM, double-buffered prefetch (R6-proven loop).
// A: MxK bf16; Bt: NxK bf16 (=B^T). Waves: (BM/WM) x (BN/WN), 64 thr each.
// XCD-chunked swizzle (grid blocks %8 == 0).
// EPI 0: dual (bx<8: interaction+linear partials, tri-K-skip, Xb-based;
//        bx>=8: h0 bf16 relu, stride 1024)
// EPI 1: bf16 + bias + relu
// EPI 3: fused out-dot + finalize (requires BN == N)
// ---------------------------------------------------------------------------
template<int BM, int BN, int WM, int WN, int EPI>
__global__ __launch_bounds__((BM / WM) * (BN / WN) * 64) void gemm_mfma(
    const short* __restrict__ A, const short* __restrict__ Bt,
    const float* __restrict__ bias, void* __restrict__ Cout,
    int N, int K,
    const short* __restrict__ Xb, const float* __restrict__ w1,
    float* __restrict__ partial,
    const float* __restrict__ c1, const float* __restrict__ c2)
{
  constexpr int WAVES_M = BM / WM, WAVES_N = BN / WN;
  constexpr int NW = WAVES_M * WAVES_N;          // total waves
  constexpr int AM = WM / 16, AN = WN / 16;
  constexpr int CA = BM / 8;                     // A 1KiB chunks per buffer
  constexpr int CB = BN / 8;
  static_assert(CA % NW == 0 && CB % NW == 0, "chunk split");
  static_assert(WAVES_N == 2, "pbuf sum assumes 2 col-waves");
  __shared__ __align__(16) short As[2][BM * 64];
  __shared__ __align__(16) short Bs[2][BN * 64];
  __shared__ float pbuf[2][BM];

  // XCD-chunked bijective swizzle (total blocks % 8 == 0 for all grids)
  const int nwgx = gridDim.x;
  const int lin  = blockIdx.y * nwgx + blockIdx.x;
  const int cpx  = (nwgx * gridDim.y) >> 3;
  const int slin = (lin & 7) * cpx + (lin >> 3);
  const int bx   = slin % nwgx;
  const int by   = slin / nwgx;

  const int tid  = threadIdx.x;
  const int wid  = tid >> 6;
  const int lane = tid & 63;
  const int wr   = wid / WAVES_N, wc = wid % WAVES_N;
  const int row0 = by * BM;
  const int col0 = bx * BN;

  const int lr8   = lane >> 3;        // chunk-local row 0..7
  const int cbase = (lane & 7) * 16;  // byte col within 128B row

  f32x4 acc[AM][AN];
  #pragma unroll
  for (int m = 0; m < AM; ++m)
    #pragma unroll
    for (int n = 0; n < AN; ++n) acc[m][n] = (f32x4)(0.f);

  auto stage = [&](int p, int k0) {
    #pragma unroll
    for (int j = 0; j < CA / NW; ++j) {
      int i = j * NW + wid;              // 1 KiB chunk = 8 rows
      int r = i * 8 + lr8;
      int cb = cbase ^ ((r & 7) << 4);   // pre-swizzled global source
      gload16((const char*)A + (((size_t)(row0 + r) * K + k0) << 1) + cb,
              (char*)&As[p][0] + i * 1024);
    }
    #pragma unroll
    for (int j = 0; j < CB / NW; ++j) {
      int i = j * NW + wid;
      int r = i * 8 + lr8;
      int cb = cbase ^ ((r & 7) << 4);
      gload16((const char*)Bt + (((size_t)(col0 + r) * K + k0) << 1) + cb,
              (char*)&Bs[p][0] + i * 1024);
    }
  };

  auto compute = [&](int p) {
    #pragma unroll
    for (int kk = 0; kk < 2; ++kk) {
      const int cb = kk * 64 + (lane >> 4) * 16;
      short8v a[AM], b[AN];
      #pragma unroll
      for (int m = 0; m < AM; ++m) {
        int r = wr * WM + m * 16 + (lane & 15);
        a[m] = *(const short8v*)((const char*)&As[p][0] + r * 128 + (cb ^ ((r & 7) << 4)));
      }
      #pragma unroll
      for (int n = 0; n < AN; ++n) {
        int r = wc * WN + n * 16 + (lane & 15);
        b[n] = *(const short8v*)((const char*)&Bs[p][0] + r * 128 + (cb ^ ((r & 7) << 4)));
      }
      #pragma unroll
      for (int m = 0; m < AM; ++m)
        #pragma unroll
        for (int n = 0; n < AN; ++n)
          acc[m][n] = __builtin_amdgcn_mfma_f32_16x16x32_bf16(a[m], b[n], acc[m][n], 0, 0, 0);
    }
  };

  // Triangular K-skip: interaction cols [col0, col0+BN) only need k < col0+BN
  int nt = K >> 6;
  if (EPI == 0 && bx < 8) {
    int need = bx * 2 + 2;
    nt = nt < need ? nt : need;
  }

  // R6-proven pipeline: stage(t+1) issued BEFORE compute(t); one barrier/tile.
  stage(0, 0);
  __syncthreads();
  for (int t = 0; t < nt; ++t) {
    if (t + 1 < nt) stage((t + 1) & 1, (t + 1) << 6);  // prefetch (in flight)
    compute(t & 1);                                     // overlaps with loads
    __syncthreads();                    // drain loads + compute-done handoff
  }

  const int cr = (lane >> 4) * 4;
  const int cc = lane & 15;

  if (EPI == 0) {
    if (bx < 8) {
      // interaction + linear partials: sum_c (acc + w1[c]) * Xb[r][c]
      float rsum[AM * 4];
      #pragma unroll
      for (int i = 0; i < AM * 4; ++i) rsum[i] = 0.f;
      #pragma unroll
      for (int m = 0; m < AM; ++m) {
        #pragma unroll
        for (int n = 0; n < AN; ++n) {
          int gc = col0 + wc * WN + n * 16 + cc;
          float w1v = (gc < FSZ) ? w1[gc] : 0.f;
          #pragma unroll
          for (int r = 0; r < 4; ++r) {
            int gr = row0 + wr * WM + m * 16 + cr + r;
            float xv = bf2f((unsigned short)Xb[(size_t)gr * 1024 + gc]);
            rsum[m * 4 + r] = fmaf(acc[m][n][r] + w1v, xv, rsum[m * 4 + r]);
          }
        }
      }
      #pragma unroll
      for (int mask = 1; mask < 16; mask <<= 1)
        #pragma unroll
        for (int i = 0; i < AM * 4; ++i)
          rsum[i] += __shfl_xor(rsum[i], mask, 64);
      if (cc == 0) {
        #pragma unroll
        for (int m = 0; m < AM; ++m)
          #pragma unroll
          for (int r = 0; r < 4; ++r)
            pbuf[wc][wr * WM + m * 16 + cr + r] = rsum[m * 4 + r];
      }
      __syncthreads();
      if (tid < BM)
        partial[(size_t)(row0 + tid) * 8 + bx] = pbuf[0][tid] + pbuf[1][tid];
    } else {
      // h0 = relu(X@W0 + B0), bf16, stride 1024
      #pragma unroll
      for (int m = 0; m < AM; ++m) {
        #pragma unroll
        for (int n = 0; n < AN; ++n) {
          int gc = col0 - 1024 + wc * WN + n * 16 + cc;
          float bv = bias[gc];
          #pragma unroll
          for (int r = 0; r < 4; ++r) {
            int gr = row0 + wr * WM + m * 16 + cr + r;
            float v = fmaxf(acc[m][n][r] + bv, 0.f);
            ((short*)Cout)[(size_t)gr * 1024 + gc] = f2bf(v);
          }
        }
      }
    }
  } else if (EPI == 1) {
    #pragma unroll
    for (int m = 0; m < AM; ++m) {
      #pragma unroll
      for (int n = 0; n < AN; ++n) {
        int gc = col0 + wc * WN + n * 16 + cc;
        float bv = bias[gc];
        #pragma unroll
        for (int r = 0; r < 4; ++r) {
          int gr = row0 + wr * WM + m * 16 + cr + r;
          float v = fmaxf(acc[m][n][r] + bv, 0.f);
          ((short*)Cout)[(size_t)gr * N + gc] = f2bf(v);
        }
      }
    }
  } else {
    // EPI 3: out[r] = sum_c relu(acc+bias[c])*oW[c] + sum_8 part[r] + c1 + c2
    float rsum[AM * 4];
    #pragma unroll
    for (int i = 0; i < AM * 4; ++i) rsum[i] = 0.f;
    #pragma unroll
    for (int m = 0; m < AM; ++m) {
      #pragma unroll
      for (int n = 0; n < AN; ++n) {
        int gc = col0 + wc * WN + n * 16 + cc;
        float bv = bias[gc];
        float ow = w1[gc];
        #pragma unroll
        for (int r = 0; r < 4; ++r) {
          float v = fmaxf(acc[m][n][r] + bv, 0.f);
          rsum[m * 4 + r] = fmaf(v, ow, rsum[m * 4 + r]);
        }
      }
    }
    #pragma unroll
    for (int mask = 1; mask < 16; mask <<= 1)
      #pragma unroll
      for (int i = 0; i < AM * 4; ++i)
        rsum[i] += __shfl_xor(rsum[i], mask, 64);
    if (cc == 0) {
      #pragma unroll
      for (int m = 0; m < AM; ++m)
        #pragma unroll
        for (int r = 0; r < 4; ++r)
          pbuf[wc][wr * WM + m * 16 + cr + r] = rsum[m * 4 + r];
    }
    __syncthreads();
    if (tid < BM) {
      int gr = row0 + tid;
      const float4* pp = (const float4*)(partial + (size_t)gr * 8);
      float4 u = pp[0], v = pp[1];
      ((float*)Cout)[gr] = pbuf[0][tid] + pbuf[1][tid]
          + u.x + u.y + u.z + u.w + v.x + v.y + v.z + v.w + c1[0] + c2[0];
    }
  }
}

// ---------------------------------------------------------------------------
extern "C" void kernel_launch(void* const* d_in, const int* in_sizes, int n_in,
                              void* d_out, int out_size, void* d_ws, size_t ws_size,
                              hipStream_t stream) {
  const float* X   = (const float*)d_in[0];
  const float* w1  = (const float*)d_in[1];
  const float* bsc = (const float*)d_in[2];
  const float* nfk = (const float*)d_in[3];
  const int*   f2f = (const int*)d_in[4];
  const float* W0  = (const float*)d_in[5];
  const float* B0  = (const float*)d_in[6];
  const float* W1  = (const float*)d_in[7];
  const float* B1  = (const float*)d_in[8];
  const float* W2  = (const float*)d_in[9];
  const float* B2  = (const float*)d_in[10];
  const float* oW  = (const float*)d_in[11];
  const float* oB  = (const float*)d_in[12];
  float* out = (float*)d_out;

  char* ws = (char*)d_ws;
  short* Xb   = (short*)(ws);                 // 8,388,608
  short* B12  = (short*)(ws + 8388608);       // 4,194,304 (Mt 0..1023, Wt0 1024..2047)
  short* Wt1  = (short*)(ws + 12582912);      // 1,048,576
  short* Wt2  = (short*)(ws + 13631488);      //   262,144
  float* part = (float*)(ws + 13893632);      //   131,072 (4096 x 8)
  short* h0   = (short*)(ws + 14680064);      // 8,388,608
  short* h1   = (short*)(ws + 23068672);      // 4,194,304
  unsigned short* nfkT = (unsigned short*)(ws + 27262976);  // 3,120,000
  // total 30,382,976 B

  // 1) prep_a: Xb, W-transposes, nfkT (bf16)
  prep_a_kernel<<<5916, 256, 0, stream>>>(X, nfk, W0, W1, W2,
                                          Xb, B12, Wt1, Wt2, nfkT);
  // 2) prep_b: Mt (coalesced via nfkT, balanced row pairs)
  prep_b_kernel<<<512, 256, 0, stream>>>(nfk, nfkT, f2f, B12);
  // 3) fused [T-partials | h0] GEMM: N=2048, K=1024 (tri-skip bx<8)
  //    256x128 tile, 8 waves, 512 thr, grid 256 = 1 block/CU
  gemm_mfma<256, 128, 64, 64, 0><<<dim3(16, 16), 512, 0, stream>>>(
      Xb, B12, B0, h0, 2048, 1024, Xb, w1, part, nullptr, nullptr);
  // 4) h1 = relu(h0 @ W1 + B1): N=512, K=1024, 64x64 tiles (512 blocks)
  gemm_mfma<64, 64, 32, 32, 1><<<dim3(8, 64), 256, 0, stream>>>(
      h0, Wt1, B1, h1, 512, 1024, nullptr, nullptr, nullptr, nullptr, nullptr);
  // 5) gemm4 + out-dot + finalize: N=BN=256, K=512 -> out[]
  gemm_mfma<32, 256, 16, 128, 3><<<dim3(1, 128), 256, 0, stream>>>(
      h1, Wt2, B2, out, 256, 512, nullptr, oW, part, bsc, oB);
}

// Round 11
// 73.844 us; speedup vs baseline: 1.0183x; 1.0183x over previous
//
#include <hip/hip_runtime.h>

// ---------------------------------------------------------------------------
// DeepFFM round 11: 5 launches, rebalanced prep.
//  1) prep_nfkT: nfkT[g][j][k] = bf16(nfk[j][g][k])   (156 blocks, tiny)
//  2) prep_main: Xb conversion + W0/W1/W2 -> bf16^T + Mt build (from nfkT)
//                all CONCURRENT in one kernel -> gather latency of Mt hides
//                under streaming Xb/W blocks (6272 blocks)
//  3) gemm12   : [T-partials | h0] = Xb @ [Mt ; Wt0]^T, N=2048, tri-K-skip
//                (reverted to R9 128x128, 2 blocks/CU — R10's 256x128 regressed)
//  4) gemm3    : h1 = relu(h0 @ W1 + B1)   (64x64, 512 blocks)
//  5) gemm4    : BN=256 (full N) + fused out-dot + finalize -> out[]
// GEMMs: bf16 MFMA 16x16x32, fp32 acc, double-buffered LDS, R6-proven
// prefetch loop (stage(t+1) before compute(t), ONE barrier per K-tile),
// XOR-swizzled LDS, XCD-chunked blockIdx swizzle (all grids %8==0).
// ---------------------------------------------------------------------------

#define BATCH   4096
#define FSZ     1000
#define NFIELDS 39
#define KDIM    40

typedef __attribute__((ext_vector_type(8))) short short8v;  // 8 x bf16
typedef __attribute__((ext_vector_type(4))) float f32x4;

__device__ __forceinline__ short f2bf(float f) {
  unsigned u = __builtin_bit_cast(unsigned, f);
  u += 0x7fff + ((u >> 16) & 1);   // RNE (finite data)
  return (short)(u >> 16);
}
__device__ __forceinline__ float bf2f(unsigned short h) {
  unsigned u = (unsigned)h << 16;
  return __builtin_bit_cast(float, u);
}

typedef const __attribute__((address_space(1))) unsigned int* gas_ptr;
typedef __attribute__((address_space(3))) unsigned int* las_ptr;
__device__ __forceinline__ void gload16(const void* g, void* l) {
  __builtin_amdgcn_global_load_lds((gas_ptr)g, (las_ptr)l, 16, 0, 0);
}

// ---------------------------------------------------------------------------
// prep_nfkT: 156 blocks (39 fields x 4 j-chunks); coalesced bf16 row writes
// ---------------------------------------------------------------------------
__global__ __launch_bounds__(256) void prep_nfkT_kernel(
    const float* __restrict__ nfk, unsigned short* __restrict__ nfkT)
{
  int g = blockIdx.x >> 2, jc = blockIdx.x & 3;
  int j = jc * 256 + threadIdx.x;
  if (j < FSZ && g < NFIELDS) {
    const float4* src = (const float4*)(nfk + ((size_t)j * NFIELDS + g) * KDIM);
    short4* dst = (short4*)(nfkT + ((size_t)g * FSZ + j) * KDIM);
    #pragma unroll
    for (int t = 0; t < KDIM / 4; ++t) {
      float4 v = src[t];
      dst[t] = make_short4(f2bf(v.x), f2bf(v.y), f2bf(v.z), f2bf(v.w));
    }
  }
}

// ---------------------------------------------------------------------------
// prep_main: block ranges (streaming + gather blocks co-resident)
//  [0,4096)     : Xb row conversion (1000 -> 1024 pad)
//  [4096,5120)  : W0^T -> B12 rows 1024..2047
//  [5120,5632)  : W1^T -> Wt1
//  [5632,5760)  : W2^T -> Wt2
//  [5760,6272)  : Mt rows {b, 1023-b} (balanced), p-side coalesced via nfkT
// ---------------------------------------------------------------------------
__device__ __forceinline__ void transp32(
    const float* __restrict__ in, short* __restrict__ out, int idx, int nx,
    int K_in, int N_in, int Kpad, float (*t)[33], int tid)
{
  int n0 = (idx % nx) * 32, k0 = (idx / nx) * 32;
  int tx = tid & 31, ty = tid >> 5;
  #pragma unroll
  for (int i = 0; i < 32; i += 8) {
    int k = k0 + ty + i, n = n0 + tx;
    t[ty + i][tx] = (k < K_in && n < N_in) ? in[(size_t)k * N_in + n] : 0.f;
  }
  __syncthreads();
  #pragma unroll
  for (int i = 0; i < 32; i += 8) {
    int n = n0 + ty + i, k = k0 + tx;
    if (n < N_in && k < Kpad) out[(size_t)n * Kpad + k] = f2bf(t[tx][ty + i]);
  }
}

__global__ __launch_bounds__(256) void prep_main_kernel(
    const float* __restrict__ X, const float* __restrict__ nfk,
    const unsigned short* __restrict__ nfkT, const int* __restrict__ f2f,
    const float* __restrict__ W0, const float* __restrict__ W1,
    const float* __restrict__ W2,
    short* __restrict__ Xb, short* __restrict__ B12,
    short* __restrict__ Wt1, short* __restrict__ Wt2)
{
  __shared__ float tbuf[32][33];
  __shared__ float C[NFIELDS * 44];   // Mt: nfk[n,:,:], stride 44
  const int bid = blockIdx.x, tid = threadIdx.x;
  if (bid < 4096) {
    int k = tid * 4;
    short4 o = make_short4(0, 0, 0, 0);
    if (k < FSZ) {
      float4 v = *(const float4*)(X + (size_t)bid * FSZ + k);
      o = make_short4(f2bf(v.x), f2bf(v.y), f2bf(v.z), f2bf(v.w));
    }
    *(short4*)(Xb + (size_t)bid * 1024 + k) = o;
  } else if (bid < 5120) {
    transp32(W0, B12 + 1024 * 1024, bid - 4096, 32, 1000, 1024, 1024, tbuf, tid);
  } else if (bid < 5632) {
    transp32(W1, Wt1, bid - 5120, 16, 1024, 512, 1024, tbuf, tid);
  } else if (bid < 5760) {
    transp32(W2, Wt2, bid - 5632, 8, 512, 256, 512, tbuf, tid);
  } else {
    const int pb = bid - 5760;          // 0..511
    #pragma unroll
    for (int ri = 0; ri < 2; ++ri) {
      const int n = ri ? (1023 - pb) : pb;
      __syncthreads();                  // prior C readers done
      if (n < FSZ) {
        for (int t = tid; t < NFIELDS * KDIM; t += 256)
          C[(t / KDIM) * 44 + (t % KDIM)] = nfk[(size_t)n * (NFIELDS * KDIM) + t];
      }
      __syncthreads();
      int fn = (n < FSZ) ? f2f[n] : 0;
      const unsigned short* pbase = nfkT + (size_t)fn * FSZ * KDIM;
      #pragma unroll
      for (int kk = 0; kk < 4; ++kk) {
        int k = kk * 256 + tid;
        float s = 0.f;
        if (n < FSZ && k < n) {
          int fk = f2f[k];
          const short8v* p = (const short8v*)(pbase + (size_t)k * KDIM);
          const float* q = &C[fk * 44];
          #pragma unroll
          for (int t = 0; t < 5; ++t) {
            short8v v = p[t];
            #pragma unroll
            for (int e = 0; e < 8; ++e)
              s = fmaf(bf2f((unsigned short)v[e]), q[t * 8 + e], s);
          }
        }
        B12[(size_t)n * 1024 + k] = f2bf(s);
      }
    }
  }
}

// ---------------------------------------------------------------------------
// bf16 MFMA GEMM, double-buffered prefetch (R6-proven loop).
// A: MxK bf16; Bt: NxK bf16 (=B^T). Waves: (BM/WM) x (BN/WN), 64 thr each.
// XCD-chunked swizzle (grid blocks %8 == 0).
// EPI 0: dual (bx<8: interaction+linear partials, tri-K-skip, Xb-based;
//        bx>=8: h0 bf16 relu, stride 1024)
// EPI 1: bf16 + bias + relu
// EPI 3: fused out-dot + finalize (requires BN == N)
// ---------------------------------------------------------------------------
template<int BM, int BN, int WM, int WN, int EPI>
__global__ __launch_bounds__((BM / WM) * (BN / WN) * 64) void gemm_mfma(
    const short* __restrict__ A, const short* __restrict__ Bt,
    const float* __restrict__ bias, void* __restrict__ Cout,
    int N, int K,
    const short* __restrict__ Xb, const float* __restrict__ w1,
    float* __restrict__ partial,
    const float* __restrict__ c1, const float* __restrict__ c2)
{
  constexpr int WAVES_M = BM / WM, WAVES_N = BN / WN;
  constexpr int NW = WAVES_M * WAVES_N;          // total waves
  constexpr int AM = WM / 16, AN = WN / 16;
  constexpr int CA = BM / 8;                     // A 1KiB chunks per buffer
  constexpr int CB = BN / 8;
  static_assert(CA % NW == 0 && CB % NW == 0, "chunk split");
  static_assert(WAVES_N == 2, "pbuf sum assumes 2 col-waves");
  __shared__ __align__(16) short As[2][BM * 64];
  __shared__ __align__(16) short Bs[2][BN * 64];
  __shared__ float pbuf[2][BM];

  // XCD-chunked bijective swizzle (total blocks % 8 == 0 for all grids)
  const int nwgx = gridDim.x;
  const int lin  = blockIdx.y * nwgx + blockIdx.x;
  const int cpx  = (nwgx * gridDim.y) >> 3;
  const int slin = (lin & 7) * cpx + (lin >> 3);
  const int bx   = slin % nwgx;
  const int by   = slin / nwgx;

  const int tid  = threadIdx.x;
  const int wid  = tid >> 6;
  const int lane = tid & 63;
  const int wr   = wid / WAVES_N, wc = wid % WAVES_N;
  const int row0 = by * BM;
  const int col0 = bx * BN;

  const int lr8   = lane >> 3;        // chunk-local row 0..7
  const int cbase = (lane & 7) * 16;  // byte col within 128B row

  f32x4 acc[AM][AN];
  #pragma unroll
  for (int m = 0; m < AM; ++m)
    #pragma unroll
    for (int n = 0; n < AN; ++n) acc[m][n] = (f32x4)(0.f);

  auto stage = [&](int p, int k0) {
    #pragma unroll
    for (int j = 0; j < CA / NW; ++j) {
      int i = j * NW + wid;              // 1 KiB chunk = 8 rows
      int r = i * 8 + lr8;
      int cb = cbase ^ ((r & 7) << 4);   // pre-swizzled global source
      gload16((const char*)A + (((size_t)(row0 + r) * K + k0) << 1) + cb,
              (char*)&As[p][0] + i * 1024);
    }
    #pragma unroll
    for (int j = 0; j < CB / NW; ++j) {
      int i = j * NW + wid;
      int r = i * 8 + lr8;
      int cb = cbase ^ ((r & 7) << 4);
      gload16((const char*)Bt + (((size_t)(col0 + r) * K + k0) << 1) + cb,
              (char*)&Bs[p][0] + i * 1024);
    }
  };

  auto compute = [&](int p) {
    #pragma unroll
    for (int kk = 0; kk < 2; ++kk) {
      const int cb = kk * 64 + (lane >> 4) * 16;
      short8v a[AM], b[AN];
      #pragma unroll
      for (int m = 0; m < AM; ++m) {
        int r = wr * WM + m * 16 + (lane & 15);
        a[m] = *(const short8v*)((const char*)&As[p][0] + r * 128 + (cb ^ ((r & 7) << 4)));
      }
      #pragma unroll
      for (int n = 0; n < AN; ++n) {
        int r = wc * WN + n * 16 + (lane & 15);
        b[n] = *(const short8v*)((const char*)&Bs[p][0] + r * 128 + (cb ^ ((r & 7) << 4)));
      }
      #pragma unroll
      for (int m = 0; m < AM; ++m)
        #pragma unroll
        for (int n = 0; n < AN; ++n)
          acc[m][n] = __builtin_amdgcn_mfma_f32_16x16x32_bf16(a[m], b[n], acc[m][n], 0, 0, 0);
    }
  };

  // Triangular K-skip: interaction cols [col0, col0+BN) only need k < col0+BN
  int nt = K >> 6;
  if (EPI == 0 && bx < 8) {
    int need = bx * 2 + 2;
    nt = nt < need ? nt : need;
  }

  // R6-proven pipeline: stage(t+1) issued BEFORE compute(t); one barrier/tile.
  stage(0, 0);
  __syncthreads();
  for (int t = 0; t < nt; ++t) {
    if (t + 1 < nt) stage((t + 1) & 1, (t + 1) << 6);  // prefetch (in flight)
    compute(t & 1);                                     // overlaps with loads
    __syncthreads();                    // drain loads + compute-done handoff
  }

  const int cr = (lane >> 4) * 4;
  const int cc = lane & 15;

  if (EPI == 0) {
    if (bx < 8) {
      // interaction + linear partials: sum_c (acc + w1[c]) * Xb[r][c]
      float rsum[AM * 4];
      #pragma unroll
      for (int i = 0; i < AM * 4; ++i) rsum[i] = 0.f;
      #pragma unroll
      for (int m = 0; m < AM; ++m) {
        #pragma unroll
        for (int n = 0; n < AN; ++n) {
          int gc = col0 + wc * WN + n * 16 + cc;
          float w1v = (gc < FSZ) ? w1[gc] : 0.f;
          #pragma unroll
          for (int r = 0; r < 4; ++r) {
            int gr = row0 + wr * WM + m * 16 + cr + r;
            float xv = bf2f((unsigned short)Xb[(size_t)gr * 1024 + gc]);
            rsum[m * 4 + r] = fmaf(acc[m][n][r] + w1v, xv, rsum[m * 4 + r]);
          }
        }
      }
      #pragma unroll
      for (int mask = 1; mask < 16; mask <<= 1)
        #pragma unroll
        for (int i = 0; i < AM * 4; ++i)
          rsum[i] += __shfl_xor(rsum[i], mask, 64);
      if (cc == 0) {
        #pragma unroll
        for (int m = 0; m < AM; ++m)
          #pragma unroll
          for (int r = 0; r < 4; ++r)
            pbuf[wc][wr * WM + m * 16 + cr + r] = rsum[m * 4 + r];
      }
      __syncthreads();
      if (tid < BM)
        partial[(size_t)(row0 + tid) * 8 + bx] = pbuf[0][tid] + pbuf[1][tid];
    } else {
      // h0 = relu(X@W0 + B0), bf16, stride 1024
      #pragma unroll
      for (int m = 0; m < AM; ++m) {
        #pragma unroll
        for (int n = 0; n < AN; ++n) {
          int gc = col0 - 1024 + wc * WN + n * 16 + cc;
          float bv = bias[gc];
          #pragma unroll
          for (int r = 0; r < 4; ++r) {
            int gr = row0 + wr * WM + m * 16 + cr + r;
            float v = fmaxf(acc[m][n][r] + bv, 0.f);
            ((short*)Cout)[(size_t)gr * 1024 + gc] = f2bf(v);
          }
        }
      }
    }
  } else if (EPI == 1) {
    #pragma unroll
    for (int m = 0; m < AM; ++m) {
      #pragma unroll
      for (int n = 0; n < AN; ++n) {
        int gc = col0 + wc * WN + n * 16 + cc;
        float bv = bias[gc];
        #pragma unroll
        for (int r = 0; r < 4; ++r) {
          int gr = row0 + wr * WM + m * 16 + cr + r;
          float v = fmaxf(acc[m][n][r] + bv, 0.f);
          ((short*)Cout)[(size_t)gr * N + gc] = f2bf(v);
        }
      }
    }
  } else {
    // EPI 3: out[r] = sum_c relu(acc+bias[c])*oW[c] + sum_8 part[r] + c1 + c2
    float rsum[AM * 4];
    #pragma unroll
    for (int i = 0; i < AM * 4; ++i) rsum[i] = 0.f;
    #pragma unroll
    for (int m = 0; m < AM; ++m) {
      #pragma unroll
      for (int n = 0; n < AN; ++n) {
        int gc = col0 + wc * WN + n * 16 + cc;
        float bv = bias[gc];
        float ow = w1[gc];
        #pragma unroll
        for (int r = 0; r < 4; ++r) {
          float v = fmaxf(acc[m][n][r] + bv, 0.f);
          rsum[m * 4 + r] = fmaf(v, ow, rsum[m * 4 + r]);
        }
      }
    }
    #pragma unroll
    for (int mask = 1; mask < 16; mask <<= 1)
      #pragma unroll
      for (int i = 0; i < AM * 4; ++i)
        rsum[i] += __shfl_xor(rsum[i], mask, 64);
    if (cc == 0) {
      #pragma unroll
      for (int m = 0; m < AM; ++m)
        #pragma unroll
        for (int r = 0; r < 4; ++r)
          pbuf[wc][wr * WM + m * 16 + cr + r] = rsum[m * 4 + r];
    }
    __syncthreads();
    if (tid < BM) {
      int gr = row0 + tid;
      const float4* pp = (const float4*)(partial + (size_t)gr * 8);
      float4 u = pp[0], v = pp[1];
      ((float*)Cout)[gr] = pbuf[0][tid] + pbuf[1][tid]
          + u.x + u.y + u.z + u.w + v.x + v.y + v.z + v.w + c1[0] + c2[0];
    }
  }
}

// ---------------------------------------------------------------------------
extern "C" void kernel_launch(void* const* d_in, const int* in_sizes, int n_in,
                              void* d_out, int out_size, void* d_ws, size_t ws_size,
                              hipStream_t stream) {
  const float* X   = (const float*)d_in[0];
  const float* w1  = (const float*)d_in[1];
  const float* bsc = (const float*)d_in[2];
  const float* nfk = (const float*)d_in[3];
  const int*   f2f = (const int*)d_in[4];
  const float* W0  = (const float*)d_in[5];
  const float* B0  = (const float*)d_in[6];
  const float* W1  = (const float*)d_in[7];
  const float* B1  = (const float*)d_in[8];
  const float* W2  = (const float*)d_in[9];
  const float* B2  = (const float*)d_in[10];
  const float* oW  = (const float*)d_in[11];
  const float* oB  = (const float*)d_in[12];
  float* out = (float*)d_out;

  char* ws = (char*)d_ws;
  short* Xb   = (short*)(ws);                 // 8,388,608
  short* B12  = (short*)(ws + 8388608);       // 4,194,304 (Mt 0..1023, Wt0 1024..2047)
  short* Wt1  = (short*)(ws + 12582912);      // 1,048,576
  short* Wt2  = (short*)(ws + 13631488);      //   262,144
  float* part = (float*)(ws + 13893632);      //   131,072 (4096 x 8)
  short* h0   = (short*)(ws + 14680064);      // 8,388,608
  short* h1   = (short*)(ws + 23068672);      // 4,194,304
  unsigned short* nfkT = (unsigned short*)(ws + 27262976);  // 3,120,000
  // total 30,382,976 B

  // 1) prep_nfkT: tiny producer for the Mt gather
  prep_nfkT_kernel<<<156, 256, 0, stream>>>(nfk, nfkT);
  // 2) prep_main: Xb + W-transposes + Mt concurrently (latency hiding)
  prep_main_kernel<<<6272, 256, 0, stream>>>(X, nfk, nfkT, f2f, W0, W1, W2,
                                             Xb, B12, Wt1, Wt2);
  // 3) fused [T-partials | h0] GEMM: N=2048, K=1024 (tri-skip bx<8)
  //    128x128 tile (R9 config: 512 blocks, 2 blocks/CU)
  gemm_mfma<128, 128, 64, 64, 0><<<dim3(16, 32), 256, 0, stream>>>(
      Xb, B12, B0, h0, 2048, 1024, Xb, w1, part, nullptr, nullptr);
  // 4) h1 = relu(h0 @ W1 + B1): N=512, K=1024, 64x64 tiles (512 blocks)
  gemm_mfma<64, 64, 32, 32, 1><<<dim3(8, 64), 256, 0, stream>>>(
      h0, Wt1, B1, h1, 512, 1024, nullptr, nullptr, nullptr, nullptr, nullptr);
  // 5) gemm4 + out-dot + finalize: N=BN=256, K=512 -> out[]
  gemm_mfma<32, 256, 16, 128, 3><<<dim3(1, 128), 256, 0, stream>>>(
      h1, Wt2, B2, out, 256, 512, nullptr, oW, part, bsc, oB);
}

// Round 12
// 72.611 us; speedup vs baseline: 1.0356x; 1.0170x over previous
//
#include <hip/hip_runtime.h>

// ---------------------------------------------------------------------------
// DeepFFM round 12: 5 launches. 8-wave GEMM blocks (TLP for latency-bound GEMM).
//  1) prep_nfkT: nfkT[g][j][k] = bf16(nfk[j][g][k])   (156 blocks, tiny)
//  2) prep_main: Xb conversion + W0/W1/W2 -> bf16^T + Mt build (concurrent)
//  3) gemm12   : [T-partials | h0] = Xb @ [Mt ; Wt0]^T, N=2048, tri-K-skip
//                128x128 tile, 8 waves (512 thr, 2x4) -> 16 waves/CU (2 blk/CU)
//  4) gemm3    : h1 = relu(h0 @ W1 + B1), 64x64 tile, 8 waves (4x2)
//  5) gemm4    : BN=256 (full N) + fused out-dot + finalize -> out[] (4 waves)
// Rationale: R8's fused counter run showed MfmaUtil 2.9% -> GEMMs are
// latency-bound at 2 waves/SIMD; doubling waves/block doubles TLP with
// identical LDS traffic and block count. Loop = R6-proven prefetch
// (stage(t+1) before compute(t), ONE barrier per K-tile, race-free).
// XOR-swizzled LDS, XCD-chunked blockIdx swizzle.
// ---------------------------------------------------------------------------

#define BATCH   4096
#define FSZ     1000
#define NFIELDS 39
#define KDIM    40

typedef __attribute__((ext_vector_type(8))) short short8v;  // 8 x bf16
typedef __attribute__((ext_vector_type(4))) float f32x4;

__device__ __forceinline__ short f2bf(float f) {
  unsigned u = __builtin_bit_cast(unsigned, f);
  u += 0x7fff + ((u >> 16) & 1);   // RNE (finite data)
  return (short)(u >> 16);
}
__device__ __forceinline__ float bf2f(unsigned short h) {
  unsigned u = (unsigned)h << 16;
  return __builtin_bit_cast(float, u);
}

typedef const __attribute__((address_space(1))) unsigned int* gas_ptr;
typedef __attribute__((address_space(3))) unsigned int* las_ptr;
__device__ __forceinline__ void gload16(const void* g, void* l) {
  __builtin_amdgcn_global_load_lds((gas_ptr)g, (las_ptr)l, 16, 0, 0);
}

// ---------------------------------------------------------------------------
// prep_nfkT: 156 blocks (39 fields x 4 j-chunks); coalesced bf16 row writes
// ---------------------------------------------------------------------------
__global__ __launch_bounds__(256) void prep_nfkT_kernel(
    const float* __restrict__ nfk, unsigned short* __restrict__ nfkT)
{
  int g = blockIdx.x >> 2, jc = blockIdx.x & 3;
  int j = jc * 256 + threadIdx.x;
  if (j < FSZ && g < NFIELDS) {
    const float4* src = (const float4*)(nfk + ((size_t)j * NFIELDS + g) * KDIM);
    short4* dst = (short4*)(nfkT + ((size_t)g * FSZ + j) * KDIM);
    #pragma unroll
    for (int t = 0; t < KDIM / 4; ++t) {
      float4 v = src[t];
      dst[t] = make_short4(f2bf(v.x), f2bf(v.y), f2bf(v.z), f2bf(v.w));
    }
  }
}

// ---------------------------------------------------------------------------
// prep_main: block ranges (streaming + gather blocks co-resident)
//  [0,4096)     : Xb row conversion (1000 -> 1024 pad)
//  [4096,5120)  : W0^T -> B12 rows 1024..2047
//  [5120,5632)  : W1^T -> Wt1
//  [5632,5760)  : W2^T -> Wt2
//  [5760,6272)  : Mt rows {b, 1023-b} (balanced), p-side coalesced via nfkT
// ---------------------------------------------------------------------------
__device__ __forceinline__ void transp32(
    const float* __restrict__ in, short* __restrict__ out, int idx, int nx,
    int K_in, int N_in, int Kpad, float (*t)[33], int tid)
{
  int n0 = (idx % nx) * 32, k0 = (idx / nx) * 32;
  int tx = tid & 31, ty = tid >> 5;
  #pragma unroll
  for (int i = 0; i < 32; i += 8) {
    int k = k0 + ty + i, n = n0 + tx;
    t[ty + i][tx] = (k < K_in && n < N_in) ? in[(size_t)k * N_in + n] : 0.f;
  }
  __syncthreads();
  #pragma unroll
  for (int i = 0; i < 32; i += 8) {
    int n = n0 + ty + i, k = k0 + tx;
    if (n < N_in && k < Kpad) out[(size_t)n * Kpad + k] = f2bf(t[tx][ty + i]);
  }
}

__global__ __launch_bounds__(256) void prep_main_kernel(
    const float* __restrict__ X, const float* __restrict__ nfk,
    const unsigned short* __restrict__ nfkT, const int* __restrict__ f2f,
    const float* __restrict__ W0, const float* __restrict__ W1,
    const float* __restrict__ W2,
    short* __restrict__ Xb, short* __restrict__ B12,
    short* __restrict__ Wt1, short* __restrict__ Wt2)
{
  __shared__ float tbuf[32][33];
  __shared__ float C[NFIELDS * 44];   // Mt: nfk[n,:,:], stride 44
  const int bid = blockIdx.x, tid = threadIdx.x;
  if (bid < 4096) {
    int k = tid * 4;
    short4 o = make_short4(0, 0, 0, 0);
    if (k < FSZ) {
      float4 v = *(const float4*)(X + (size_t)bid * FSZ + k);
      o = make_short4(f2bf(v.x), f2bf(v.y), f2bf(v.z), f2bf(v.w));
    }
    *(short4*)(Xb + (size_t)bid * 1024 + k) = o;
  } else if (bid < 5120) {
    transp32(W0, B12 + 1024 * 1024, bid - 4096, 32, 1000, 1024, 1024, tbuf, tid);
  } else if (bid < 5632) {
    transp32(W1, Wt1, bid - 5120, 16, 1024, 512, 1024, tbuf, tid);
  } else if (bid < 5760) {
    transp32(W2, Wt2, bid - 5632, 8, 512, 256, 512, tbuf, tid);
  } else {
    const int pb = bid - 5760;          // 0..511
    #pragma unroll
    for (int ri = 0; ri < 2; ++ri) {
      const int n = ri ? (1023 - pb) : pb;
      __syncthreads();                  // prior C readers done
      if (n < FSZ) {
        for (int t = tid; t < NFIELDS * KDIM; t += 256)
          C[(t / KDIM) * 44 + (t % KDIM)] = nfk[(size_t)n * (NFIELDS * KDIM) + t];
      }
      __syncthreads();
      int fn = (n < FSZ) ? f2f[n] : 0;
      const unsigned short* pbase = nfkT + (size_t)fn * FSZ * KDIM;
      #pragma unroll
      for (int kk = 0; kk < 4; ++kk) {
        int k = kk * 256 + tid;
        float s = 0.f;
        if (n < FSZ && k < n) {
          int fk = f2f[k];
          const short8v* p = (const short8v*)(pbase + (size_t)k * KDIM);
          const float* q = &C[fk * 44];
          #pragma unroll
          for (int t = 0; t < 5; ++t) {
            short8v v = p[t];
            #pragma unroll
            for (int e = 0; e < 8; ++e)
              s = fmaf(bf2f((unsigned short)v[e]), q[t * 8 + e], s);
          }
        }
        B12[(size_t)n * 1024 + k] = f2bf(s);
      }
    }
  }
}

// ---------------------------------------------------------------------------
// bf16 MFMA GEMM, double-buffered prefetch (R6-proven loop).
// A: MxK bf16; Bt: NxK bf16 (=B^T). Waves: (BM/WM) x (BN/WN), 64 thr each.
// XCD-chunked swizzle (grid blocks %8 == 0).
// EPI 0: dual (bx<8: interaction+linear partials, tri-K-skip, Xb-based;
//        bx>=8: h0 bf16 relu, stride 1024)
// EPI 1: bf16 + bias + relu
// EPI 3: fused out-dot + finalize (requires BN == N)
// ---------------------------------------------------------------------------
template<int BM, int BN, int WM, int WN, int EPI>
__global__ __launch_bounds__((BM / WM) * (BN / WN) * 64) void gemm_mfma(
    const short* __restrict__ A, const short* __restrict__ Bt,
    const float* __restrict__ bias, void* __restrict__ Cout,
    int N, int K,
    const short* __restrict__ Xb, const float* __restrict__ w1,
    float* __restrict__ partial,
    const float* __restrict__ c1, const float* __restrict__ c2)
{
  constexpr int WAVES_M = BM / WM, WAVES_N = BN / WN;
  constexpr int NW = WAVES_M * WAVES_N;          // total waves
  constexpr int AM = WM / 16, AN = WN / 16;
  constexpr int CA = BM / 8;                     // A 1KiB chunks per buffer
  constexpr int CB = BN / 8;
  static_assert(CA % NW == 0 && CB % NW == 0, "chunk split");
  __shared__ __align__(16) short As[2][BM * 64];
  __shared__ __align__(16) short Bs[2][BN * 64];
  __shared__ float pbuf[WAVES_N][BM];

  // XCD-chunked bijective swizzle (total blocks % 8 == 0 for all grids)
  const int nwgx = gridDim.x;
  const int lin  = blockIdx.y * nwgx + blockIdx.x;
  const int cpx  = (nwgx * gridDim.y) >> 3;
  const int slin = (lin & 7) * cpx + (lin >> 3);
  const int bx   = slin % nwgx;
  const int by   = slin / nwgx;

  const int tid  = threadIdx.x;
  const int wid  = tid >> 6;
  const int lane = tid & 63;
  const int wr   = wid / WAVES_N, wc = wid % WAVES_N;
  const int row0 = by * BM;
  const int col0 = bx * BN;

  const int lr8   = lane >> 3;        // chunk-local row 0..7
  const int cbase = (lane & 7) * 16;  // byte col within 128B row

  f32x4 acc[AM][AN];
  #pragma unroll
  for (int m = 0; m < AM; ++m)
    #pragma unroll
    for (int n = 0; n < AN; ++n) acc[m][n] = (f32x4)(0.f);

  auto stage = [&](int p, int k0) {
    #pragma unroll
    for (int j = 0; j < CA / NW; ++j) {
      int i = j * NW + wid;              // 1 KiB chunk = 8 rows
      int r = i * 8 + lr8;
      int cb = cbase ^ ((r & 7) << 4);   // pre-swizzled global source
      gload16((const char*)A + (((size_t)(row0 + r) * K + k0) << 1) + cb,
              (char*)&As[p][0] + i * 1024);
    }
    #pragma unroll
    for (int j = 0; j < CB / NW; ++j) {
      int i = j * NW + wid;
      int r = i * 8 + lr8;
      int cb = cbase ^ ((r & 7) << 4);
      gload16((const char*)Bt + (((size_t)(col0 + r) * K + k0) << 1) + cb,
              (char*)&Bs[p][0] + i * 1024);
    }
  };

  auto compute = [&](int p) {
    #pragma unroll
    for (int kk = 0; kk < 2; ++kk) {
      const int cb = kk * 64 + (lane >> 4) * 16;
      short8v a[AM], b[AN];
      #pragma unroll
      for (int m = 0; m < AM; ++m) {
        int r = wr * WM + m * 16 + (lane & 15);
        a[m] = *(const short8v*)((const char*)&As[p][0] + r * 128 + (cb ^ ((r & 7) << 4)));
      }
      #pragma unroll
      for (int n = 0; n < AN; ++n) {
        int r = wc * WN + n * 16 + (lane & 15);
        b[n] = *(const short8v*)((const char*)&Bs[p][0] + r * 128 + (cb ^ ((r & 7) << 4)));
      }
      #pragma unroll
      for (int m = 0; m < AM; ++m)
        #pragma unroll
        for (int n = 0; n < AN; ++n)
          acc[m][n] = __builtin_amdgcn_mfma_f32_16x16x32_bf16(a[m], b[n], acc[m][n], 0, 0, 0);
    }
  };

  // Triangular K-skip: interaction cols [col0, col0+BN) only need k < col0+BN
  int nt = K >> 6;
  if (EPI == 0 && bx < 8) {
    int need = bx * 2 + 2;
    nt = nt < need ? nt : need;
  }

  // R6-proven pipeline: stage(t+1) issued BEFORE compute(t); one barrier/tile.
  stage(0, 0);
  __syncthreads();
  for (int t = 0; t < nt; ++t) {
    if (t + 1 < nt) stage((t + 1) & 1, (t + 1) << 6);  // prefetch (in flight)
    compute(t & 1);                                     // overlaps with loads
    __syncthreads();                    // drain loads + compute-done handoff
  }

  const int cr = (lane >> 4) * 4;
  const int cc = lane & 15;

  if (EPI == 0) {
    if (bx < 8) {
      // interaction + linear partials: sum_c (acc + w1[c]) * Xb[r][c]
      float rsum[AM * 4];
      #pragma unroll
      for (int i = 0; i < AM * 4; ++i) rsum[i] = 0.f;
      #pragma unroll
      for (int m = 0; m < AM; ++m) {
        #pragma unroll
        for (int n = 0; n < AN; ++n) {
          int gc = col0 + wc * WN + n * 16 + cc;
          float w1v = (gc < FSZ) ? w1[gc] : 0.f;
          #pragma unroll
          for (int r = 0; r < 4; ++r) {
            int gr = row0 + wr * WM + m * 16 + cr + r;
            float xv = bf2f((unsigned short)Xb[(size_t)gr * 1024 + gc]);
            rsum[m * 4 + r] = fmaf(acc[m][n][r] + w1v, xv, rsum[m * 4 + r]);
          }
        }
      }
      #pragma unroll
      for (int mask = 1; mask < 16; mask <<= 1)
        #pragma unroll
        for (int i = 0; i < AM * 4; ++i)
          rsum[i] += __shfl_xor(rsum[i], mask, 64);
      if (cc == 0) {
        #pragma unroll
        for (int m = 0; m < AM; ++m)
          #pragma unroll
          for (int r = 0; r < 4; ++r)
            pbuf[wc][wr * WM + m * 16 + cr + r] = rsum[m * 4 + r];
      }
      __syncthreads();
      if (tid < BM) {
        float s = 0.f;
        #pragma unroll
        for (int w = 0; w < WAVES_N; ++w) s += pbuf[w][tid];
        partial[(size_t)(row0 + tid) * 8 + bx] = s;
      }
    } else {
      // h0 = relu(X@W0 + B0), bf16, stride 1024
      #pragma unroll
      for (int m = 0; m < AM; ++m) {
        #pragma unroll
        for (int n = 0; n < AN; ++n) {
          int gc = col0 - 1024 + wc * WN + n * 16 + cc;
          float bv = bias[gc];
          #pragma unroll
          for (int r = 0; r < 4; ++r) {
            int gr = row0 + wr * WM + m * 16 + cr + r;
            float v = fmaxf(acc[m][n][r] + bv, 0.f);
            ((short*)Cout)[(size_t)gr * 1024 + gc] = f2bf(v);
          }
        }
      }
    }
  } else if (EPI == 1) {
    #pragma unroll
    for (int m = 0; m < AM; ++m) {
      #pragma unroll
      for (int n = 0; n < AN; ++n) {
        int gc = col0 + wc * WN + n * 16 + cc;
        float bv = bias[gc];
        #pragma unroll
        for (int r = 0; r < 4; ++r) {
          int gr = row0 + wr * WM + m * 16 + cr + r;
          float v = fmaxf(acc[m][n][r] + bv, 0.f);
          ((short*)Cout)[(size_t)gr * N + gc] = f2bf(v);
        }
      }
    }
  } else {
    // EPI 3: out[r] = sum_c relu(acc+bias[c])*oW[c] + sum_8 part[r] + c1 + c2
    float rsum[AM * 4];
    #pragma unroll
    for (int i = 0; i < AM * 4; ++i) rsum[i] = 0.f;
    #pragma unroll
    for (int m = 0; m < AM; ++m) {
      #pragma unroll
      for (int n = 0; n < AN; ++n) {
        int gc = col0 + wc * WN + n * 16 + cc;
        float bv = bias[gc];
        float ow = w1[gc];
        #pragma unroll
        for (int r = 0; r < 4; ++r) {
          float v = fmaxf(acc[m][n][r] + bv, 0.f);
          rsum[m * 4 + r] = fmaf(v, ow, rsum[m * 4 + r]);
        }
      }
    }
    #pragma unroll
    for (int mask = 1; mask < 16; mask <<= 1)
      #pragma unroll
      for (int i = 0; i < AM * 4; ++i)
        rsum[i] += __shfl_xor(rsum[i], mask, 64);
    if (cc == 0) {
      #pragma unroll
      for (int m = 0; m < AM; ++m)
        #pragma unroll
        for (int r = 0; r < 4; ++r)
          pbuf[wc][wr * WM + m * 16 + cr + r] = rsum[m * 4 + r];
    }
    __syncthreads();
    if (tid < BM) {
      int gr = row0 + tid;
      const float4* pp = (const float4*)(partial + (size_t)gr * 8);
      float4 u = pp[0], v = pp[1];
      float s = 0.f;
      #pragma unroll
      for (int w = 0; w < WAVES_N; ++w) s += pbuf[w][tid];
      ((float*)Cout)[gr] = s
          + u.x + u.y + u.z + u.w + v.x + v.y + v.z + v.w + c1[0] + c2[0];
    }
  }
}

// ---------------------------------------------------------------------------
extern "C" void kernel_launch(void* const* d_in, const int* in_sizes, int n_in,
                              void* d_out, int out_size, void* d_ws, size_t ws_size,
                              hipStream_t stream) {
  const float* X   = (const float*)d_in[0];
  const float* w1  = (const float*)d_in[1];
  const float* bsc = (const float*)d_in[2];
  const float* nfk = (const float*)d_in[3];
  const int*   f2f = (const int*)d_in[4];
  const float* W0  = (const float*)d_in[5];
  const float* B0  = (const float*)d_in[6];
  const float* W1  = (const float*)d_in[7];
  const float* B1  = (const float*)d_in[8];
  const float* W2  = (const float*)d_in[9];
  const float* B2  = (const float*)d_in[10];
  const float* oW  = (const float*)d_in[11];
  const float* oB  = (const float*)d_in[12];
  float* out = (float*)d_out;

  char* ws = (char*)d_ws;
  short* Xb   = (short*)(ws);                 // 8,388,608
  short* B12  = (short*)(ws + 8388608);       // 4,194,304 (Mt 0..1023, Wt0 1024..2047)
  short* Wt1  = (short*)(ws + 12582912);      // 1,048,576
  short* Wt2  = (short*)(ws + 13631488);      //   262,144
  float* part = (float*)(ws + 13893632);      //   131,072 (4096 x 8)
  short* h0   = (short*)(ws + 14680064);      // 8,388,608
  short* h1   = (short*)(ws + 23068672);      // 4,194,304
  unsigned short* nfkT = (unsigned short*)(ws + 27262976);  // 3,120,000
  // total 30,382,976 B

  // 1) prep_nfkT: tiny producer for the Mt gather
  prep_nfkT_kernel<<<156, 256, 0, stream>>>(nfk, nfkT);
  // 2) prep_main: Xb + W-transposes + Mt concurrently (latency hiding)
  prep_main_kernel<<<6272, 256, 0, stream>>>(X, nfk, nfkT, f2f, W0, W1, W2,
                                             Xb, B12, Wt1, Wt2);
  // 3) fused [T-partials | h0] GEMM: N=2048, K=1024 (tri-skip bx<8)
  //    128x128 tile, 8 waves (2x4), 512 thr -> 16 waves/CU at 2 blocks/CU
  gemm_mfma<128, 128, 64, 32, 0><<<dim3(16, 32), 512, 0, stream>>>(
      Xb, B12, B0, h0, 2048, 1024, Xb, w1, part, nullptr, nullptr);
  // 4) h1 = relu(h0 @ W1 + B1): N=512, K=1024, 64x64 tiles, 8 waves (4x2)
  gemm_mfma<64, 64, 16, 32, 1><<<dim3(8, 64), 512, 0, stream>>>(
      h0, Wt1, B1, h1, 512, 1024, nullptr, nullptr, nullptr, nullptr, nullptr);
  // 5) gemm4 + out-dot + finalize: N=BN=256, K=512 -> out[] (4 waves)
  gemm_mfma<32, 256, 16, 128, 3><<<dim3(1, 128), 256, 0, stream>>>(
      h1, Wt2, B2, out, 256, 512, nullptr, oW, part, bsc, oB);
}